// Round 11
// baseline (490.570 us; speedup 1.0000x reference)
//
#include <hip/hip_runtime.h>
#include <cstdint>

typedef unsigned short u16;
typedef __attribute__((ext_vector_type(8))) short short8;
typedef __attribute__((ext_vector_type(8))) unsigned short ushort8;
typedef __attribute__((ext_vector_type(4))) float floatx4;
typedef __attribute__((ext_vector_type(8))) _Float16 half8;

#define S_LEN 1024
#define BATCH 64
#define EDIM 1024
#define UDIM 1024
#define VOCAB 32000
#define NTOT (3 * UDIM)        // 3072
#define CT 32                  // timesteps per scan chunk
#define NC (S_LEN / CT)        // 32 chunks
#define NWT 3072               // conv_wt tiles (32x32x3)
#define NCE 4096               // conv_emb grid-stride blocks

__device__ __forceinline__ u16 f2bf(float x) {
  unsigned u = __float_as_uint(x);
  return (u16)((u + 0x7fffu + ((u >> 16) & 1u)) >> 16);  // RNE, inputs are finite
}

// async global->LDS, 16B per lane. HW writes LDS LINEARLY: wave-uniform base
// + lane*16 (m104/m108). All swizzling must live in the GLOBAL address.
__device__ __forceinline__ void async16(const u16* g, u16* s) {
  __builtin_amdgcn_global_load_lds(
      (__attribute__((address_space(1))) void*)(uintptr_t)g,
      (__attribute__((address_space(3))) void*)(uintptr_t)s,
      16, 0, 0);
}

__device__ __forceinline__ float sigm(float x) {
  return __builtin_amdgcn_rcpf(1.f + __expf(-x));
}

// ---- fused preprocessing: one launch for both weight transpose + emb cast ----
// blocks [0, NWT): transpose+convert W[E,U] fp32 -> Wt[U,E] bf16 (3 mats);
// blocks [NWT, NWT+NCE): grid-stride emb fp32 -> bf16, 32B in / 16B out.
__global__ __launch_bounds__(256) void conv_pre(
    const float* __restrict__ Wf, const float* __restrict__ Wi,
    const float* __restrict__ Wh, u16* __restrict__ wtB,
    const float4* __restrict__ embIn, u16* __restrict__ embOut, int n8) {
  const int b = blockIdx.x;
  const int tid = threadIdx.x;
  if (b < NWT) {
    __shared__ float t[32][33];
    const int z = b >> 10;            // 0..2  matrix
    const int rem = b & 1023;
    const int by = (rem >> 5) * 32;   // k (input row)
    const int bx = (rem & 31) * 32;   // n (input col)
    const float* W = (z == 0) ? Wf : ((z == 1) ? Wi : Wh);
    const int tx = tid & 31, ty = tid >> 5;  // ty 0..7
    for (int j = 0; j < 32; j += 8)
      t[ty + j][tx] = W[(size_t)(by + ty + j) * UDIM + bx + tx];
    __syncthreads();
    u16* out = wtB + (size_t)z * UDIM * EDIM;
    for (int j = 0; j < 32; j += 8)
      out[(size_t)(bx + ty + j) * EDIM + by + tx] = f2bf(t[tx][ty + j]);
  } else {
    const int stride = NCE * 256;
    for (int i = (b - NWT) * 256 + tid; i < n8; i += stride) {
      float4 v0 = embIn[2 * i];
      float4 v1 = embIn[2 * i + 1];
      ushort8 o;
      o[0] = f2bf(v0.x); o[1] = f2bf(v0.y); o[2] = f2bf(v0.z); o[3] = f2bf(v0.w);
      o[4] = f2bf(v1.x); o[5] = f2bf(v1.y); o[6] = f2bf(v1.z); o[7] = f2bf(v1.w);
      *(ushort8*)&embOut[(size_t)i * 8] = o;
    }
  }
}

// ---- per-VOCAB-row gate table: 3-gate GEMM + gate nonlinearity epilogue ----
// Third-M launch (mcount m-tiles from mbase) so the rocprof top-5 threshold
// drops to ~68us and any hidden kernel above that surfaces. K-loop is the
// R1-measured optimum (194-198us full-M, 48.5% MfmaUtil): 10x async16 ->
// __syncthreads -> 48 MFMA -> __syncthreads. Schedule experiments R3/R4/R6
// all regressed; implicit wave overlap at 3 blocks/CU captures the gain.
__global__ __launch_bounds__(256, 3) void gate_gemm(
    const u16* __restrict__ embB, const u16* __restrict__ wtB,
    const float* __restrict__ bfp, const float* __restrict__ bip,
    const float* __restrict__ bhp, u16* __restrict__ FG, int mbase) {
  __shared__ __align__(16) u16 SM[128 * 64 + 192 * 64];  // 40 KB (As | Bs)
  u16* As = SM;
  u16* Bs = SM + 128 * 64;

  const int tid = threadIdx.x;
  const int wave = tid >> 6;
  const int lane = tid & 63;

  // XCD map (bijective over 16*mcount blocks): XCD x owns utiles {2x, 2x+1};
  // consecutive slots on an XCD share the mtile -> A fetched once into that
  // XCD's L2, twin block hits; the XCD's 2 B-slices stay L2-resident.
  const int g = blockIdx.x;
  const int x = g & 7;
  const int s = g >> 3;              // 0..2*mcount-1
  const int mtile = mbase + (s >> 1);
  const int utile = x * 2 + (s & 1); // 0..15
  const int m0 = mtile * 128;
  const int u0 = utile * 64;

  // staging maps, XOR-swizzled at 16B-chunk granularity in the GLOBAL source:
  // LDS slot (row r, chunk c) holds global chunk c^(r&7) -> conflict-free
  // ds_read_b128 on the read side. LDS dest stays linear (idx*16B).
  const u16* gA[4]; int loA[4];
  const u16* gB[6]; int loB[6];
#pragma unroll
  for (int j = 0; j < 4; ++j) {
    int idx = j * 256 + tid;
    int r = idx >> 3;
    int cg = (idx & 7) ^ (r & 7);
    gA[j] = embB + (size_t)(m0 + r) * EDIM + cg * 8;
    loA[j] = idx * 8;
  }
#pragma unroll
  for (int j = 0; j < 6; ++j) {
    int idx = j * 256 + tid;
    int r = idx >> 3;                            // 0..191
    int gr = (r >> 6) * UDIM + u0 + (r & 63);    // gate*1024 + u
    int cg = (idx & 7) ^ (r & 7);
    gB[j] = wtB + (size_t)gr * EDIM + cg * 8;
    loB[j] = idx * 8;
  }

  floatx4 acc[8][3] = {};
  const int fr = lane & 15;
  const int fq = lane >> 4;
  const int fr7 = fr & 7;
  const int un = wave * 16 + fr;  // u-col within block's 64

  for (int k0 = 0; k0 < EDIM; k0 += 64) {
#pragma unroll
    for (int j = 0; j < 4; ++j) async16(gA[j] + k0, &As[loA[j]]);
#pragma unroll
    for (int j = 0; j < 6; ++j) async16(gB[j] + k0, &Bs[loB[j]]);
    __syncthreads();
#pragma unroll
    for (int kk = 0; kk < 2; ++kk) {
      const int swz = ((kk * 4 + fq) ^ fr7) * 8;
      short8 b0 = *(const short8*)&Bs[(0 * 64 + un) * 64 + swz];
      short8 b1 = *(const short8*)&Bs[(1 * 64 + un) * 64 + swz];
      short8 b2 = *(const short8*)&Bs[(2 * 64 + un) * 64 + swz];
#pragma unroll
      for (int mt = 0; mt < 8; ++mt) {
        short8 am = *(const short8*)&As[(mt * 16 + fr) * 64 + swz];
        acc[mt][0] = __builtin_amdgcn_mfma_f32_16x16x32_bf16(am, b0, acc[mt][0], 0, 0, 0);
        acc[mt][1] = __builtin_amdgcn_mfma_f32_16x16x32_bf16(am, b1, acc[mt][1], 0, 0, 0);
        acc[mt][2] = __builtin_amdgcn_mfma_f32_16x16x32_bf16(am, b2, acc[mt][2], 0, 0, 0);
      }
    }
    __syncthreads();
  }

  // ---- epilogue: gate nonlinearity -> interleaved (F,G) f16 pairs ----
  // C/D layout: col=lane&15 (u), row=(lane>>4)*4+reg. row = mt*16+fq*4+r.
  // LDS restage overlays SM (dead now). Pair-u32 write at un ^ ((fq&1)<<4)
  // spreads a wave's stores over all 32 banks (2-way, free; conflicts=0 R4-R8).
  const int ug = u0 + un;
  const float bfv = bfp[ug], biv = bip[ug], bhv = bhp[ug];
  u16* FGs = SM;  // 128 rows x 64 pairs x u32 = 32 KB
  const int up = un ^ ((fq & 1) << 4);
#pragma unroll
  for (int mt = 0; mt < 8; ++mt) {
#pragma unroll
    for (int r = 0; r < 4; ++r) {
      float fs = sigm(acc[mt][0][r] + bfv);
      float is = sigm(acc[mt][1][r] + biv);
      float hv = acc[mt][2][r] + bhv;
      float inv = __builtin_amdgcn_rcpf(fs + is);
      float fn = fs * inv;
      float gv = is * inv * hv;
      int row = mt * 16 + fq * 4 + r;
      unsigned pkfg = (unsigned)__builtin_bit_cast(u16, (_Float16)fn) |
                      ((unsigned)__builtin_bit_cast(u16, (_Float16)gv) << 16);
      *(unsigned*)&FGs[row * 128 + up * 2] = pkfg;
    }
  }
  __syncthreads();
  // 128 rows x 16 chunks of 16B; un-group cc was written at cc ^ (fqpar<<2)
#pragma unroll
  for (int j = 0; j < 8; ++j) {
    int idx = j * 256 + tid;
    int row = idx >> 4, cc = idx & 15;
    int ccp = cc ^ (((row >> 2) & 1) << 2);
    *(ushort8*)&FG[(size_t)(m0 + row) * (2 * UDIM) + u0 * 2 + cc * 8] =
        *(const ushort8*)&FGs[row * 128 + ccp * 8];
  }
}

// ---- gather precomputed (fn, g) pairs per token + 32-step chunk scan ----
// block = (b, chunk c): 256 threads x 4 u-cols, serial over 32 timesteps.
// Depth-2 register pipeline: rows t+1, t+2 are in flight while row t is
// converted/accumulated -- guards against the compiler serializing the
// gather behind the FMA chain (suspected cause of ~160us hidden cost).
// Fully unrolled so the prefetch registers stay statically indexed.
__global__ __launch_bounds__(256) void scan_gather(
    const int* __restrict__ sent, const u16* __restrict__ FG,
    float* __restrict__ Fc, float* __restrict__ Gc) {
  const int b = blockIdx.x >> 5;
  const int c = blockIdx.x & (NC - 1);
  const int tid = threadIdx.x;
  __shared__ int toks[CT];
  if (tid < CT) toks[tid] = sent[b * S_LEN + c * CT + tid];
  __syncthreads();
  const int uo2 = tid * 8;  // u16 offset within a 2048-u16 row
  floatx4 F = {1.f, 1.f, 1.f, 1.f};
  floatx4 G = {0.f, 0.f, 0.f, 0.f};
  ushort8 r0 = *(const ushort8*)&FG[(size_t)toks[0] * (2 * UDIM) + uo2];
  ushort8 r1 = *(const ushort8*)&FG[(size_t)toks[1] * (2 * UDIM) + uo2];
#pragma unroll
  for (int t = 0; t < CT; ++t) {
    ushort8 cur = r0;
    r0 = r1;
    if (t + 2 < CT)
      r1 = *(const ushort8*)&FG[(size_t)toks[t + 2] * (2 * UDIM) + uo2];
    half8 fg = __builtin_bit_cast(half8, cur);
    floatx4 fn = {(float)fg[0], (float)fg[2], (float)fg[4], (float)fg[6]};
    floatx4 gv = {(float)fg[1], (float)fg[3], (float)fg[5], (float)fg[7]};
    G = fn * G + gv;   // h' = fn*h + g composed left-to-right
    F = F * fn;
  }
  const size_t o = (size_t)c * (BATCH * UDIM) + (size_t)b * UDIM + tid * 4;
  *(floatx4*)&Fc[o] = F;
  *(floatx4*)&Gc[o] = G;
}

// ---------------- combine chunks + MLP head ----------------
__global__ __launch_bounds__(256) void mlp_head(
    const float* __restrict__ Fc, const float* __restrict__ Gc,
    const float* __restrict__ W1, const float* __restrict__ b1,
    const float* __restrict__ W2, const float* __restrict__ b2,
    float* __restrict__ out) {
  const int b = blockIdx.x;
  const int tid = threadIdx.x;
  __shared__ float h_s[UDIM];
  __shared__ float z1[64];
  for (int u = tid; u < UDIM; u += 256) {
    float h = 0.f;
#pragma unroll
    for (int c = 0; c < NC; ++c) {
      float F = Fc[c * (BATCH * UDIM) + b * UDIM + u];
      float G = Gc[c * (BATCH * UDIM) + b * UDIM + u];
      h = F * h + G;
    }
    h_s[u] = h;
  }
  __syncthreads();
  const int j = tid >> 2, p = tid & 3;
  float partial = 0.f;
  for (int u = p * 256; u < p * 256 + 256; ++u) partial += h_s[u] * W1[u * 64 + j];
  partial += __shfl_down(partial, 1);
  partial += __shfl_down(partial, 2);
  if (p == 0) z1[j] = partial + b1[j];
  __syncthreads();
  if (tid < 64) {
    float v = z1[tid] * W2[tid];
#pragma unroll
    for (int off = 32; off > 0; off >>= 1) v += __shfl_down(v, off);
    if (tid == 0) out[b] = 1.f / (1.f + __expf(-(v + b2[0])));
  }
}

extern "C" void kernel_launch(void* const* d_in, const int* in_sizes, int n_in,
                              void* d_out, int out_size, void* d_ws, size_t ws_size,
                              hipStream_t stream) {
  const int* sent = (const int*)d_in[0];
  const float* emb = (const float*)d_in[1];
  const float* Wf = (const float*)d_in[2];
  const float* bf_ = (const float*)d_in[3];
  const float* Wi = (const float*)d_in[4];
  const float* bi_ = (const float*)d_in[5];
  const float* Wh = (const float*)d_in[6];
  const float* bh_ = (const float*)d_in[7];
  const float* W1 = (const float*)d_in[8];
  const float* b1 = (const float*)d_in[9];
  const float* W2 = (const float*)d_in[10];
  const float* b2 = (const float*)d_in[11];
  float* out = (float*)d_out;

  // workspace layout (~210 MiB)
  char* ws = (char*)d_ws;
  u16* embB = (u16*)ws;   ws += (size_t)VOCAB * EDIM * 2;         //  65,536,000
  u16* wtB = (u16*)ws;    ws += (size_t)NTOT * EDIM * 2;          //   6,291,456
  u16* FG = (u16*)ws;     ws += (size_t)VOCAB * UDIM * 2 * 2;     // 131,072,000
  float* Fc = (float*)ws; ws += (size_t)NC * BATCH * UDIM * 4;    //   8,388,608
  float* Gc = (float*)ws; ws += (size_t)NC * BATCH * UDIM * 4;    //   8,388,608

  int n8 = (int)((size_t)VOCAB * EDIM / 8);
  hipLaunchKernelGGL(conv_pre, dim3(NWT + NCE), dim3(256), 0, stream,
                     Wf, Wi, Wh, wtB, (const float4*)emb, embB, n8);
  // split M in thirds (~68us each): drops the rocprof top-5 threshold so any
  // hidden kernel >68us (suspect: scan_gather) must surface in the dump
  hipLaunchKernelGGL(gate_gemm, dim3(16 * 84), dim3(256), 0, stream,
                     embB, wtB, bf_, bi_, bh_, FG, 0);
  hipLaunchKernelGGL(gate_gemm, dim3(16 * 83), dim3(256), 0, stream,
                     embB, wtB, bf_, bi_, bh_, FG, 84);
  hipLaunchKernelGGL(gate_gemm, dim3(16 * 83), dim3(256), 0, stream,
                     embB, wtB, bf_, bi_, bh_, FG, 167);
  hipLaunchKernelGGL(scan_gather, dim3(BATCH * NC), dim3(256), 0, stream,
                     sent, FG, Fc, Gc);
  hipLaunchKernelGGL(mlp_head, dim3(BATCH), dim3(256), 0, stream, Fc, Gc, W1, b1, W2, b2, out);
}

// Round 13
// 461.871 us; speedup vs baseline: 1.0621x; 1.0621x over previous
//
#include <hip/hip_runtime.h>
#include <cstdint>

typedef unsigned short u16;
typedef __attribute__((ext_vector_type(8))) short short8;
typedef __attribute__((ext_vector_type(8))) unsigned short ushort8;
typedef __attribute__((ext_vector_type(4))) float floatx4;
typedef __attribute__((ext_vector_type(8))) _Float16 half8;

#define S_LEN 1024
#define BATCH 64
#define EDIM 1024
#define UDIM 1024
#define VOCAB 32000
#define NTOT (3 * UDIM)        // 3072
#define CT 32                  // timesteps per scan chunk
#define NC (S_LEN / CT)        // 32 chunks
#define NWT 3072               // conv_wt tiles (32x32x3)
#define NCE 4096               // conv_emb grid-stride blocks
#define GEMM_GRID 4000         // (VOCAB/128) * (NTOT/192)

__device__ __forceinline__ u16 f2bf(float x) {
  unsigned u = __float_as_uint(x);
  return (u16)((u + 0x7fffu + ((u >> 16) & 1u)) >> 16);  // RNE, inputs are finite
}

// async global->LDS, 16B per lane. HW writes LDS LINEARLY: wave-uniform base
// + lane*16 (m104/m108). All swizzling must live in the GLOBAL address.
__device__ __forceinline__ void async16(const u16* g, u16* s) {
  __builtin_amdgcn_global_load_lds(
      (__attribute__((address_space(1))) void*)(uintptr_t)g,
      (__attribute__((address_space(3))) void*)(uintptr_t)s,
      16, 0, 0);
}

__device__ __forceinline__ float sigm(float x) {
  return __builtin_amdgcn_rcpf(1.f + __expf(-x));
}

// ---- fused preprocessing: one launch for weight transpose + emb cast ----
// blocks [0, NWT): transpose+convert W[E,U] fp32 -> Wt[U,E] bf16 (3 mats);
// blocks [NWT, NWT+NCE): grid-stride emb fp32 -> bf16, 32B in / 16B out.
__global__ __launch_bounds__(256) void conv_pre(
    const float* __restrict__ Wf, const float* __restrict__ Wi,
    const float* __restrict__ Wh, u16* __restrict__ wtB,
    const float4* __restrict__ embIn, u16* __restrict__ embOut, int n8) {
  const int b = blockIdx.x;
  const int tid = threadIdx.x;
  if (b < NWT) {
    __shared__ float t[32][33];
    const int z = b >> 10;            // 0..2  matrix
    const int rem = b & 1023;
    const int by = (rem >> 5) * 32;   // k (input row)
    const int bx = (rem & 31) * 32;   // n (input col)
    const float* W = (z == 0) ? Wf : ((z == 1) ? Wi : Wh);
    const int tx = tid & 31, ty = tid >> 5;  // ty 0..7
    for (int j = 0; j < 32; j += 8)
      t[ty + j][tx] = W[(size_t)(by + ty + j) * UDIM + bx + tx];
    __syncthreads();
    u16* out = wtB + (size_t)z * UDIM * EDIM;
    for (int j = 0; j < 32; j += 8)
      out[(size_t)(bx + ty + j) * EDIM + by + tx] = f2bf(t[tx][ty + j]);
  } else {
    const int stride = NCE * 256;
    for (int i = (b - NWT) * 256 + tid; i < n8; i += stride) {
      const float4 v0 = embIn[2 * i];
      const float4 v1 = embIn[2 * i + 1];
      ushort8 o;
      o[0] = f2bf(v0.x);
      o[1] = f2bf(v0.y);
      o[2] = f2bf(v0.z);
      o[3] = f2bf(v0.w);
      o[4] = f2bf(v1.x);
      o[5] = f2bf(v1.y);
      o[6] = f2bf(v1.z);
      o[7] = f2bf(v1.w);
      *(ushort8*)&embOut[(size_t)i * 8] = o;
    }
  }
}

// ---- per-VOCAB-row gate table: 3-gate GEMM + gate nonlinearity epilogue ----
// Full-M single launch (R11 measured: the 3-way split cost +29us via tail
// underfill at 1344 blocks; 4000 blocks amortize the 768 co-resident slots).
// K-loop is the R1/R7-measured optimum (194-198us, 48.5% MfmaUtil): 10x
// async16 -> __syncthreads -> 48 MFMA -> __syncthreads. Per-wave per K=64:
// 22 ds_read_b128 (~264cy) vs 48 MFMA (~233cy) -> LDS-read-bound; structural
// ceiling ~55% for this 4-wave tile. R3/R4/R6 restructures all regressed.
__global__ __launch_bounds__(256, 3) void gate_gemm(
    const u16* __restrict__ embB, const u16* __restrict__ wtB,
    const float* __restrict__ bfp, const float* __restrict__ bip,
    const float* __restrict__ bhp, u16* __restrict__ FG) {
  __shared__ __align__(16) u16 SM[128 * 64 + 192 * 64];  // 40 KB (As | Bs)
  u16* As = SM;
  u16* Bs = SM + 128 * 64;

  const int tid = threadIdx.x;
  const int wave = tid >> 6;
  const int lane = tid & 63;

  // XCD map (bijective over 4000 blocks): XCD x owns utiles {2x, 2x+1};
  // consecutive slots on an XCD share the mtile -> A fetched once into that
  // XCD's L2, twin block hits; the XCD's 2 B-slices stay L2-resident.
  const int g = blockIdx.x;
  const int x = g & 7;
  const int s = g >> 3;              // 0..499
  const int mtile = s >> 1;          // 0..249
  const int utile = x * 2 + (s & 1); // 0..15
  const int m0 = mtile * 128;
  const int u0 = utile * 64;

  // staging maps, XOR-swizzled at 16B-chunk granularity in the GLOBAL source:
  // LDS slot (row r, chunk c) holds global chunk c^(r&7) -> conflict-free
  // ds_read_b128 on the read side. LDS dest stays linear (idx*16B).
  const u16* gA[4]; int loA[4];
  const u16* gB[6]; int loB[6];
#pragma unroll
  for (int j = 0; j < 4; ++j) {
    int idx = j * 256 + tid;
    int r = idx >> 3;
    int cg = (idx & 7) ^ (r & 7);
    gA[j] = embB + (size_t)(m0 + r) * EDIM + cg * 8;
    loA[j] = idx * 8;
  }
#pragma unroll
  for (int j = 0; j < 6; ++j) {
    int idx = j * 256 + tid;
    int r = idx >> 3;                            // 0..191
    int gr = (r >> 6) * UDIM + u0 + (r & 63);    // gate*1024 + u
    int cg = (idx & 7) ^ (r & 7);
    gB[j] = wtB + (size_t)gr * EDIM + cg * 8;
    loB[j] = idx * 8;
  }

  floatx4 acc[8][3] = {};
  const int fr = lane & 15;
  const int fq = lane >> 4;
  const int fr7 = fr & 7;
  const int un = wave * 16 + fr;  // u-col within block's 64

  for (int k0 = 0; k0 < EDIM; k0 += 64) {
#pragma unroll
    for (int j = 0; j < 4; ++j) async16(gA[j] + k0, &As[loA[j]]);
#pragma unroll
    for (int j = 0; j < 6; ++j) async16(gB[j] + k0, &Bs[loB[j]]);
    __syncthreads();
#pragma unroll
    for (int kk = 0; kk < 2; ++kk) {
      const int swz = ((kk * 4 + fq) ^ fr7) * 8;
      short8 b0 = *(const short8*)&Bs[(0 * 64 + un) * 64 + swz];
      short8 b1 = *(const short8*)&Bs[(1 * 64 + un) * 64 + swz];
      short8 b2 = *(const short8*)&Bs[(2 * 64 + un) * 64 + swz];
#pragma unroll
      for (int mt = 0; mt < 8; ++mt) {
        short8 am = *(const short8*)&As[(mt * 16 + fr) * 64 + swz];
        acc[mt][0] = __builtin_amdgcn_mfma_f32_16x16x32_bf16(am, b0, acc[mt][0], 0, 0, 0);
        acc[mt][1] = __builtin_amdgcn_mfma_f32_16x16x32_bf16(am, b1, acc[mt][1], 0, 0, 0);
        acc[mt][2] = __builtin_amdgcn_mfma_f32_16x16x32_bf16(am, b2, acc[mt][2], 0, 0, 0);
      }
    }
    __syncthreads();
  }

  // ---- epilogue: gate nonlinearity -> interleaved (F,G) f16 pairs ----
  // C/D layout: col=lane&15 (u), row=(lane>>4)*4+reg. row = mt*16+fq*4+r.
  // LDS restage overlays SM (dead now). Pair-u32 write at un ^ ((fq&1)<<4)
  // spreads a wave's stores over all 32 banks (2-way, free; conflicts=0
  // across R4-R11 measurements).
  const int ug = u0 + un;
  const float bfv = bfp[ug], biv = bip[ug], bhv = bhp[ug];
  u16* FGs = SM;  // 128 rows x 64 pairs x u32 = 32 KB
  const int up = un ^ ((fq & 1) << 4);
#pragma unroll
  for (int mt = 0; mt < 8; ++mt) {
#pragma unroll
    for (int r = 0; r < 4; ++r) {
      float fs = sigm(acc[mt][0][r] + bfv);
      float is = sigm(acc[mt][1][r] + biv);
      float hv = acc[mt][2][r] + bhv;
      float inv = __builtin_amdgcn_rcpf(fs + is);
      float fn = fs * inv;
      float gv = is * inv * hv;
      int row = mt * 16 + fq * 4 + r;
      unsigned pkfg = (unsigned)__builtin_bit_cast(u16, (_Float16)fn) |
                      ((unsigned)__builtin_bit_cast(u16, (_Float16)gv) << 16);
      *(unsigned*)&FGs[row * 128 + up * 2] = pkfg;
    }
  }
  __syncthreads();
  // 128 rows x 16 chunks of 16B; un-group cc was written at cc ^ (fqpar<<2)
#pragma unroll
  for (int j = 0; j < 8; ++j) {
    int idx = j * 256 + tid;
    int row = idx >> 4, cc = idx & 15;
    int ccp = cc ^ (((row >> 2) & 1) << 2);
    *(ushort8*)&FG[(size_t)(m0 + row) * (2 * UDIM) + u0 * 2 + cc * 8] =
        *(const ushort8*)&FGs[row * 128 + ccp * 8];
  }
}

// ---- gather precomputed (fn, g) pairs per token + 32-step chunk scan ----
// block = (b, chunk c): 256 threads x 4 u-cols, serial over 32 timesteps.
// Depth-2 register rotate: rows t+1, t+2 in flight while row t is consumed.
// 2048 blocks -> 8 blocks/CU of gather TLP.
__global__ __launch_bounds__(256) void scan_gather(
    const int* __restrict__ sent, const u16* __restrict__ FG,
    float* __restrict__ Fc, float* __restrict__ Gc) {
  const int b = blockIdx.x >> 5;
  const int c = blockIdx.x & (NC - 1);
  const int tid = threadIdx.x;
  __shared__ int toks[CT];
  if (tid < CT) toks[tid] = sent[b * S_LEN + c * CT + tid];
  __syncthreads();
  const int uo2 = tid * 8;  // u16 offset within a 2048-u16 row
  floatx4 F = {1.f, 1.f, 1.f, 1.f};
  floatx4 G = {0.f, 0.f, 0.f, 0.f};
  ushort8 ra = *(const ushort8*)&FG[(size_t)toks[0] * (2 * UDIM) + uo2];
  ushort8 rb = *(const ushort8*)&FG[(size_t)toks[1] * (2 * UDIM) + uo2];
#pragma unroll
  for (int t = 0; t < CT - 2; ++t) {
    ushort8 rc = *(const ushort8*)&FG[(size_t)toks[t + 2] * (2 * UDIM) + uo2];
    half8 fg = __builtin_bit_cast(half8, ra);
    ra = rb;
    rb = rc;
    floatx4 fn = {(float)fg[0], (float)fg[2], (float)fg[4], (float)fg[6]};
    floatx4 gv = {(float)fg[1], (float)fg[3], (float)fg[5], (float)fg[7]};
    G = fn * G + gv;   // h' = fn*h + g composed left-to-right
    F = F * fn;
  }
#pragma unroll
  for (int t = 0; t < 2; ++t) {  // drain the 2 in-flight rows
    half8 fg = __builtin_bit_cast(half8, ra);
    ra = rb;
    floatx4 fn = {(float)fg[0], (float)fg[2], (float)fg[4], (float)fg[6]};
    floatx4 gv = {(float)fg[1], (float)fg[3], (float)fg[5], (float)fg[7]};
    G = fn * G + gv;
    F = F * fn;
  }
  const size_t o = (size_t)c * (BATCH * UDIM) + (size_t)b * UDIM + tid * 4;
  *(floatx4*)&Fc[o] = F;
  *(floatx4*)&Gc[o] = G;
}

// ---------------- combine chunks + MLP head ----------------
__global__ __launch_bounds__(256) void mlp_head(
    const float* __restrict__ Fc, const float* __restrict__ Gc,
    const float* __restrict__ W1, const float* __restrict__ b1,
    const float* __restrict__ W2, const float* __restrict__ b2,
    float* __restrict__ out) {
  const int b = blockIdx.x;
  const int tid = threadIdx.x;
  __shared__ float h_s[UDIM];
  __shared__ float z1[64];
  for (int u = tid; u < UDIM; u += 256) {
    float h = 0.f;
#pragma unroll
    for (int c = 0; c < NC; ++c) {
      float F = Fc[c * (BATCH * UDIM) + b * UDIM + u];
      float G = Gc[c * (BATCH * UDIM) + b * UDIM + u];
      h = F * h + G;
    }
    h_s[u] = h;
  }
  __syncthreads();
  const int j = tid >> 2, p = tid & 3;
  float partial = 0.f;
  for (int u = p * 256; u < p * 256 + 256; ++u) partial += h_s[u] * W1[u * 64 + j];
  partial += __shfl_down(partial, 1);
  partial += __shfl_down(partial, 2);
  if (p == 0) z1[j] = partial + b1[j];
  __syncthreads();
  if (tid < 64) {
    float v = z1[tid] * W2[tid];
#pragma unroll
    for (int off = 32; off > 0; off >>= 1) v += __shfl_down(v, off);
    if (tid == 0) out[b] = 1.f / (1.f + __expf(-(v + b2[0])));
  }
}

extern "C" void kernel_launch(void* const* d_in, const int* in_sizes, int n_in,
                              void* d_out, int out_size, void* d_ws, size_t ws_size,
                              hipStream_t stream) {
  const int* sent = (const int*)d_in[0];
  const float* emb = (const float*)d_in[1];
  const float* Wf = (const float*)d_in[2];
  const float* bf_ = (const float*)d_in[3];
  const float* Wi = (const float*)d_in[4];
  const float* bi_ = (const float*)d_in[5];
  const float* Wh = (const float*)d_in[6];
  const float* bh_ = (const float*)d_in[7];
  const float* W1 = (const float*)d_in[8];
  const float* b1 = (const float*)d_in[9];
  const float* W2 = (const float*)d_in[10];
  const float* b2 = (const float*)d_in[11];
  float* out = (float*)d_out;

  // workspace layout (~210 MiB)
  char* ws = (char*)d_ws;
  u16* embB = (u16*)ws;   ws += (size_t)VOCAB * EDIM * 2;         //  65,536,000
  u16* wtB = (u16*)ws;    ws += (size_t)NTOT * EDIM * 2;          //   6,291,456
  u16* FG = (u16*)ws;     ws += (size_t)VOCAB * UDIM * 2 * 2;     // 131,072,000
  float* Fc = (float*)ws; ws += (size_t)NC * BATCH * UDIM * 4;    //   8,388,608
  float* Gc = (float*)ws; ws += (size_t)NC * BATCH * UDIM * 4;    //   8,388,608

  const int n8 = (int)((size_t)VOCAB * EDIM / 8);
  hipLaunchKernelGGL(conv_pre, dim3(NWT + NCE), dim3(256), 0, stream,
                     Wf, Wi, Wh, wtB, (const float4*)emb, embB, n8);
  hipLaunchKernelGGL(gate_gemm, dim3(GEMM_GRID), dim3(256), 0, stream,
                     embB, wtB, bf_, bi_, bh_, FG);
  hipLaunchKernelGGL(scan_gather, dim3(BATCH * NC), dim3(256), 0, stream,
                     sent, FG, Fc, Gc);
  hipLaunchKernelGGL(mlp_head, dim3(BATCH), dim3(256), 0, stream, Fc, Gc, W1, b1, W2, b2, out);
}